// Round 11
// baseline (6080.106 us; speedup 1.0000x reference)
//
#include <hip/hip_runtime.h>

#define NF 32
#define HDIM 256
#define SLEN 256
#define BATCH 1024

typedef float f32x4 __attribute__((ext_vector_type(4)));
typedef __bf16 bf16x8 __attribute__((ext_vector_type(8)));
typedef unsigned int u32x4 __attribute__((ext_vector_type(4)));
typedef unsigned short u16;
typedef unsigned long long u64;

#define MFMA __builtin_amdgcn_mfma_f32_16x16x32_bf16

// ---- ws layout ----
// uint4 slots [0, 672KB): packed MFMA B-fragments
// bytes [1MB, 5MB):  Wt bf16 [32 f][65536 k], k = s*256 + h
// bytes [6MB):       cnt u32 [64 g][257]
// bytes [8MB, ~143MB): hst bf16 [1024 b][257 slot][256 h]  (slot s = h_s)
#define WHH_O 0       // 64 j * 8 t * 64 l
#define WIH_O 32768
#define WOUT_O 36864
#define WLAT_O 37888
#define PREP1_N 41984
#define WT_BYTE (1u << 20)
#define CNT_BYTE (6u << 20)
#define HST_BYTE (8u << 20)
#define CNT_N (64 * 257)

__device__ __forceinline__ u16 f2bf(float x) {
  __bf16 b = (__bf16)x;
  return __builtin_bit_cast(u16, b);
}
__device__ __forceinline__ float bf2f(u16 u) {
  unsigned int v = ((unsigned int)u) << 16;
  return __builtin_bit_cast(float, v);
}
__device__ __forceinline__ unsigned int pk2(float a, float b) {
  return (unsigned int)f2bf(a) | ((unsigned int)f2bf(b) << 16);
}
__device__ __forceinline__ float sigf(float x) {
  return __fdividef(1.0f, 1.0f + __expf(-x));
}
__device__ __forceinline__ float tanhf_(float x) {
  return 1.0f - __fdividef(2.0f, __expf(2.0f * x) + 1.0f);
}

// Pack W_hh / W_ih / W_out / W_lat into MFMA B-fragment order (unchanged).
__global__ void prep_weights(const float* __restrict__ Whh, const float* __restrict__ Wih,
                             const float* __restrict__ Wout, const float* __restrict__ Wlat,
                             uint4* __restrict__ ws) {
  int i = blockIdx.x * 256 + threadIdx.x;
  if (i >= PREP1_N) return;
  int l = i & 63;
  int c16 = l & 15, g4 = l >> 4;
  const float* src;
  if (i < WIH_O) {
    int t = (i >> 6) & 7, j = i >> 9;
    src = Whh + (j * 16 + c16) * 256 + t * 32 + 8 * g4;
  } else if (i < WOUT_O) {
    int ii = i - WIH_O;
    int j = ii >> 6;
    src = Wih + (j * 16 + c16) * 32 + 8 * g4;
  } else if (i < WLAT_O) {
    int ii = i - WOUT_O;
    int t = (ii >> 6) & 7, j = ii >> 9;
    src = Wout + (j * 16 + c16) * 256 + t * 32 + 8 * g4;
  } else {
    int ii = i - WLAT_O;
    int t = (ii >> 6) & 1, j = ii >> 7;
    src = Wlat + (j * 16 + c16) * 64 + t * 32 + 8 * g4;
  }
  uint4 P;
  P.x = pk2(src[0], src[1]);
  P.y = pk2(src[2], src[3]);
  P.z = pk2(src[4], src[5]);
  P.w = pk2(src[6], src[7]);
  ws[i] = P;
}

// Transpose W_sig [32 f][h*256+s] (f32) -> Wt [32 f][s*256+h] (bf16). Unchanged.
__global__ void prep_wt(const float* __restrict__ Wsig, unsigned short* __restrict__ Wt) {
  __shared__ float tile[32][257];
  int f = blockIdx.x >> 3, hb = blockIdx.x & 7;
  int tid = threadIdx.x;
  const float* src = Wsig + f * (HDIM * SLEN) + hb * 32 * 256;
#pragma unroll
  for (int i = 0; i < 32; ++i) tile[i][tid] = src[i * 256 + tid];
  __syncthreads();
  int s = tid;
  unsigned short tmp[32];
#pragma unroll
  for (int h = 0; h < 32; ++h) tmp[h] = f2bf(tile[h][s]);
  uint4* dst = (uint4*)(Wt + f * 65536 + s * 256 + hb * 32);
  const uint4* tsrc = (const uint4*)tmp;
#pragma unroll
  for (int j = 0; j < 4; ++j) dst[j] = tsrc[j];
}

__global__ void prep_zero(unsigned int* __restrict__ cnt) {
  int i = blockIdx.x * 256 + threadIdx.x;
  if (i < CNT_N) cnt[i] = 0;
}

// ---------------- the scan: 256 WGs = 64 groups x 4 gate-slices ----------------
// Slice p owns h-cols [64p,64p+64) and all 4 gates for them (W_hh slice = 32
// fragments = 128 VGPR, register-resident at 2 waves/SIMD = 256-reg budget).
// Per-step exchange: publish own h (2KB) as relaxed u64 agent-atomics into hst;
// peers load 6KB and compute tanh locally. 8 waves: 0-3 gates, 4-5 x-GEMM.
__global__ __attribute__((amdgpu_flat_work_group_size(512, 512)))
__attribute__((amdgpu_waves_per_eu(2, 2))) void lstm_scan(
    const float* __restrict__ z, const float* __restrict__ b_lat,
    const float* __restrict__ b_ih, const float* __restrict__ b_hh,
    const float* __restrict__ b_out, const uint4* __restrict__ ws,
    u64* __restrict__ hst, unsigned int* __restrict__ cnt,
    float* __restrict__ out) {
  __shared__ __align__(16) u16 hbuf[16][256];   // 8KB (row-swizzled)
  __shared__ __align__(16) u16 thbuf[16][256];  // 8KB (row-swizzled)
  __shared__ __align__(16) u16 xbuf[16][32];    // 1KB
  __shared__ __align__(16) u16 zb[16][64];      // 2KB

  const int tid = threadIdx.x, w = tid >> 6, l = tid & 63;
  const int c16 = l & 15, g4 = l >> 4, r0 = g4 * 4;
  const int g = blockIdx.x >> 2, p = blockIdx.x & 3;
  const int q = w & 3;
  const int swz = (c16 & 7) << 3;

  unsigned int* mycnt = cnt + g * 257;

  // ---- register-resident weights ----
  // gate waves: W_hh slice (4 j-tiles x 8 kt = 128 VGPR) + W_ih (16) + bias
  u32x4 wp[4][8];
  u32x4 wihr[4];
  float biasv[4];
#pragma unroll
  for (int G = 0; G < 4; ++G) {
    int j = G * 16 + 4 * p + q;
#pragma unroll
    for (int kt = 0; kt < 8; ++kt)
      wp[G][kt] = __builtin_bit_cast(u32x4, ws[WHH_O + (j * 8 + kt) * 64 + l]);
    wihr[G] = __builtin_bit_cast(u32x4, ws[WIH_O + j * 64 + l]);
    int n = G * 256 + p * 64 + q * 16 + c16;
    biasv[G] = b_ih[n] + b_hh[n];
  }
  // x waves (4,5): W_out j-tile jx
  const int jx = w - 4;
  u32x4 wo[8];
  float bo = 0.f;
  if (w == 4 || w == 5) {
#pragma unroll
    for (int t = 0; t < 8; ++t)
      wo[t] = __builtin_bit_cast(u32x4, ws[WOUT_O + (jx * 8 + t) * 64 + l]);
    bo = b_out[jx * 16 + c16];
  }

  // ---- init: z -> zb, xbuf = 0 ----
  {
    int i0 = tid, i1 = tid + 512;
    zb[i0 >> 6][i0 & 63] = f2bf(z[(g * 16 + (i0 >> 6)) * 64 + (i0 & 63)]);
    zb[i1 >> 6][i1 & 63] = f2bf(z[(g * 16 + (i1 >> 6)) * 64 + (i1 & 63)]);
    xbuf[tid >> 5][tid & 31] = 0;
  }
  __syncthreads();

  // hc = z @ W_lat^T + b_lat (own cols only)
  float cst[4] = {0.f, 0.f, 0.f, 0.f};
  if (w < 4) {
    bf16x8 za0 = *reinterpret_cast<const bf16x8*>(&zb[c16][8 * g4]);
    bf16x8 za1 = *reinterpret_cast<const bf16x8*>(&zb[c16][32 + 8 * g4]);
    int jh = 4 * p + q, jc = 16 + 4 * p + q;
    int lc = p * 64 + q * 16 + c16;
    float blh = b_lat[lc], blc = b_lat[256 + lc];
    f32x4 ah = {blh, blh, blh, blh}, ac = {blc, blc, blc, blc};
    ah = MFMA(za0, *reinterpret_cast<const bf16x8*>(ws + WLAT_O + (jh * 2 + 0) * 64 + l), ah, 0, 0, 0);
    ah = MFMA(za1, *reinterpret_cast<const bf16x8*>(ws + WLAT_O + (jh * 2 + 1) * 64 + l), ah, 0, 0, 0);
    ac = MFMA(za0, *reinterpret_cast<const bf16x8*>(ws + WLAT_O + (jc * 2 + 0) * 64 + l), ac, 0, 0, 0);
    ac = MFMA(za1, *reinterpret_cast<const bf16x8*>(ws + WLAT_O + (jc * 2 + 1) * 64 + l), ac, 0, 0, 0);
#pragma unroll
    for (int v = 0; v < 4; ++v) {
      cst[v] = ac[v];
      float hh = ah[v];
      int rr = r0 + v, sw = (rr & 7) << 3;
      hbuf[rr][lc ^ sw] = f2bf(hh);
      thbuf[rr][lc ^ sw] = f2bf(tanhf_(hh));
    }
  }
  __syncthreads();
  // publish h_0 (slot 0)
  if (tid < 256) {
    int r = tid >> 4, c4 = tid & 15;
    int ci = ((p * 64 + c4 * 4) ^ ((r & 7) << 3)) >> 2;
    u64 v = ((const u64*)&hbuf[r][0])[ci];
    __hip_atomic_store(&hst[((u64)(g * 16 + r) * 257 + 0) * 64 + p * 16 + c4], v,
                       __ATOMIC_RELAXED, __HIP_MEMORY_SCOPE_AGENT);
  }
  asm volatile("s_waitcnt vmcnt(0)" ::: "memory");
  __syncthreads();
  if (tid == 0)
    __hip_atomic_fetch_add(&mycnt[0], 1u, __ATOMIC_RELEASE, __HIP_MEMORY_SCOPE_AGENT);

  // ---- the scan: s = 0..256 (s==256 is the x_256 tail) ----
  for (int s = 0; s <= 256; ++s) {
    if (tid == 0) {
      while (__hip_atomic_load(&mycnt[s], __ATOMIC_RELAXED, __HIP_MEMORY_SCOPE_AGENT) < 4u)
        __builtin_amdgcn_s_sleep(1);
    }
    __syncthreads();  // B0
    __builtin_amdgcn_fence(__ATOMIC_ACQUIRE, "agent");
    // P1: load 3 peers' h_s (768 u64), local tanh -> hbuf/thbuf
#pragma unroll
    for (int rep = 0; rep < 2; ++rep) {
      int t = tid + rep * 512;
      if (t < 768) {
        int pp = t >> 8, rem = t & 255;
        int r = rem >> 4, c4 = rem & 15;
        int peer = (p + 1 + pp) & 3;
        u64 v = __hip_atomic_load(&hst[((u64)(g * 16 + r) * 257 + s) * 64 + peer * 16 + c4],
                                  __ATOMIC_RELAXED, __HIP_MEMORY_SCOPE_AGENT);
        u64 tv = 0;
#pragma unroll
        for (int e = 0; e < 4; ++e) {
          float hv = bf2f((u16)(v >> (16 * e)));
          tv |= ((u64)f2bf(tanhf_(hv))) << (16 * e);
        }
        int ci = ((peer * 64 + c4 * 4) ^ ((r & 7) << 3)) >> 2;
        ((u64*)&hbuf[r][0])[ci] = v;
        ((u64*)&thbuf[r][0])[ci] = tv;
      }
    }
    __syncthreads();  // B1

    const bool gate_on = (w < 4) && (s < 256);
    const bool x_on = (w == 4 || w == 5) && (s >= 1);
    // P2: gates: h@W_hh (32 MFMA, all weights in regs) || x waves: x_s = th_s@W_out
    f32x4 acc[4];
    if (gate_on) {
#pragma unroll
      for (int G = 0; G < 4; ++G)
        acc[G] = (f32x4){biasv[G], biasv[G], biasv[G], biasv[G]};
#pragma unroll
      for (int kt = 0; kt < 8; ++kt) {
        bf16x8 afr = *reinterpret_cast<const bf16x8*>(&hbuf[c16][(kt * 32 + 8 * g4) ^ swz]);
        acc[0] = MFMA(afr, __builtin_bit_cast(bf16x8, wp[0][kt]), acc[0], 0, 0, 0);
        acc[1] = MFMA(afr, __builtin_bit_cast(bf16x8, wp[1][kt]), acc[1], 0, 0, 0);
        acc[2] = MFMA(afr, __builtin_bit_cast(bf16x8, wp[2][kt]), acc[2], 0, 0, 0);
        acc[3] = MFMA(afr, __builtin_bit_cast(bf16x8, wp[3][kt]), acc[3], 0, 0, 0);
      }
    }
    f32x4 xacc = {0.f, 0.f, 0.f, 0.f};
    if (x_on) {
      xacc = (f32x4){bo, bo, bo, bo};
#pragma unroll
      for (int kt = 0; kt < 8; ++kt) {
        bf16x8 ta = *reinterpret_cast<const bf16x8*>(&thbuf[c16][(kt * 32 + 8 * g4) ^ swz]);
        xacc = MFMA(ta, __builtin_bit_cast(bf16x8, wo[kt]), xacc, 0, 0, 0);
      }
      const int f = jx * 16 + c16;
#pragma unroll
      for (int v = 0; v < 4; ++v) xbuf[r0 + v][f] = f2bf(xacc[v]);
    }
    __syncthreads();  // B2

    // P3: gates: + x@W_ih, elementwise, write own h/th; x waves: mu store
    if (gate_on) {
      bf16x8 xfr = *reinterpret_cast<const bf16x8*>(&xbuf[c16][8 * g4]);
#pragma unroll
      for (int G = 0; G < 4; ++G)
        acc[G] = MFMA(xfr, __builtin_bit_cast(bf16x8, wihr[G]), acc[G], 0, 0, 0);
      const int lc = p * 64 + q * 16 + c16;
#pragma unroll
      for (int v = 0; v < 4; ++v) {
        float iv = acc[0][v], fv = acc[1][v], gv = acc[2][v], ov = acc[3][v];
        float cc = sigf(fv) * cst[v] + sigf(iv) * tanhf_(gv);
        cst[v] = cc;
        float hh = sigf(ov) * tanhf_(cc);
        float th = tanhf_(hh);
        int rr = r0 + v, sw = (rr & 7) << 3;
        hbuf[rr][lc ^ sw] = f2bf(hh);
        thbuf[rr][lc ^ sw] = f2bf(th);
      }
    }
    if (x_on) {
      // mu col s-1 = x_s (fire-and-forget scalar stores; L2 merges)
      const int f = jx * 16 + c16;
#pragma unroll
      for (int v = 0; v < 4; ++v)
        out[(g * 16 + r0 + v) * (NF * SLEN) + f * SLEN + (s - 1)] = xacc[v];
    }
    if (s < 256) {
      __syncthreads();  // B3: own h_{s+1} in hbuf
      // P4: publish own h_{s+1} (slot s+1)
      if (tid < 256) {
        int r = tid >> 4, c4 = tid & 15;
        int ci = ((p * 64 + c4 * 4) ^ ((r & 7) << 3)) >> 2;
        u64 v = ((const u64*)&hbuf[r][0])[ci];
        __hip_atomic_store(&hst[((u64)(g * 16 + r) * 257 + (s + 1)) * 64 + p * 16 + c4], v,
                           __ATOMIC_RELAXED, __HIP_MEMORY_SCOPE_AGENT);
      }
      asm volatile("s_waitcnt vmcnt(0)" ::: "memory");
      __syncthreads();  // B4: all waves' stores drained
      if (tid == 0)
        __hip_atomic_fetch_add(&mycnt[s + 1], 1u, __ATOMIC_RELEASE, __HIP_MEMORY_SCOPE_AGENT);
    }
  }
}

// sigma = softplus(hs_flat @ W_sig^T + b_sig); hst has 257 slots, h_s at slot s.
__global__ __launch_bounds__(512) void sigma_gemm(
    const unsigned short* __restrict__ hst, const unsigned short* __restrict__ Wt,
    const float* __restrict__ b_sig, float* __restrict__ out) {
  __shared__ float sred[8][16][32];
  const int tid = threadIdx.x;
  const int w = tid >> 6;
  const int l = tid & 63;
  const int c16 = l & 15;
  const int g4 = l >> 4;
  const int wg = blockIdx.x;

  const int b = (wg << 2) + (c16 & 3);
  const unsigned short* ap = hst + ((u64)b * 257 + 1 + w * 32) * 256 + (g4 << 3);
  const unsigned short* bp0 = Wt + (c16 << 16) + ((w * 32) << 8) + (g4 << 3);
  const unsigned short* bp1 = Wt + ((16 + c16) << 16) + ((w * 32) << 8) + (g4 << 3);

  f32x4 a0 = {0.f, 0.f, 0.f, 0.f}, a1 = {0.f, 0.f, 0.f, 0.f};
#pragma unroll 8
  for (int kk = 0; kk < 256; ++kk) {
    int off = (kk >> 3) * 256 + ((kk & 7) << 5);
    bf16x8 av = *reinterpret_cast<const bf16x8*>(ap + off);
    a0 = MFMA(av, *reinterpret_cast<const bf16x8*>(bp0 + off), a0, 0, 0, 0);
    a1 = MFMA(av, *reinterpret_cast<const bf16x8*>(bp1 + off), a1, 0, 0, 0);
  }
#pragma unroll
  for (int v = 0; v < 4; ++v) {
    sred[w][g4 * 4 + v][c16] = a0[v];
    sred[w][g4 * 4 + v][16 + c16] = a1[v];
  }
  __syncthreads();
  int bb = tid >> 5, f = tid & 31;
  if (bb < 4) {
    float acc = b_sig[f];
#pragma unroll
    for (int ww = 0; ww < 8; ++ww) acc += sred[ww][bb][f];
    float sp = fmaxf(acc, 0.0f) + log1pf(__expf(-fabsf(acc)));
    out[BATCH * NF * SLEN + ((wg << 2) + bb) * NF + f] = sp;
  }
}

extern "C" void kernel_launch(void* const* d_in, const int* in_sizes, int n_in,
                              void* d_out, int out_size, void* d_ws, size_t ws_size,
                              hipStream_t stream) {
  (void)in_sizes; (void)n_in; (void)out_size; (void)ws_size;
  const float* z     = (const float*)d_in[0];
  const float* W_lat = (const float*)d_in[1];
  const float* b_lat = (const float*)d_in[2];
  const float* W_ih  = (const float*)d_in[3];
  const float* b_ih  = (const float*)d_in[4];
  const float* W_hh  = (const float*)d_in[5];
  const float* b_hh  = (const float*)d_in[6];
  const float* W_out = (const float*)d_in[7];
  const float* b_out = (const float*)d_in[8];
  const float* W_sig = (const float*)d_in[9];
  const float* b_sig = (const float*)d_in[10];
  char* wsb = (char*)d_ws;
  uint4* ws = (uint4*)wsb;
  unsigned short* Wt = (unsigned short*)(wsb + WT_BYTE);
  unsigned int* cnt = (unsigned int*)(wsb + CNT_BYTE);
  u64* hst = (u64*)(wsb + HST_BYTE);
  float* out = (float*)d_out;

  prep_weights<<<(PREP1_N + 255) / 256, 256, 0, stream>>>(W_hh, W_ih, W_out, W_lat, ws);
  prep_wt<<<256, 256, 0, stream>>>(W_sig, Wt);
  prep_zero<<<(CNT_N + 255) / 256, 256, 0, stream>>>(cnt);
  lstm_scan<<<256, 512, 0, stream>>>(z, b_lat, b_ih, b_hh, b_out, ws, hst, cnt, out);
  sigma_gemm<<<256, 512, 0, stream>>>((const unsigned short*)(wsb + HST_BYTE), Wt, b_sig, out);
}

// Round 12
// 2933.637 us; speedup vs baseline: 2.0725x; 2.0725x over previous
//
#include <hip/hip_runtime.h>

#define NF 32
#define HDIM 256
#define SLEN 256
#define BATCH 1024

typedef float f32x4 __attribute__((ext_vector_type(4)));
typedef __bf16 bf16x8 __attribute__((ext_vector_type(8)));
typedef unsigned short u16;

#define MFMA __builtin_amdgcn_mfma_f32_16x16x32_bf16

// ---- ws layout ----
// uint4 slots [0, 672KB): packed MFMA B-fragments
// bytes [1MB, 5MB):   Wt bf16 [32 f][65536 k], k = s*256 + h   (W_sig transposed)
// bytes [8MB, 136MB): hst bf16 [1024 b][256 s][256 h]
#define WHH_O 0       // 64 j * 8 t * 64 l  = 32768 slots
#define WIH_O 32768   // 64 j * 64 l        =  4096
#define WOUT_O 36864  //  2 j * 8 t * 64 l  =  1024
#define WLAT_O 37888  // 32 j * 2 t * 64 l  =  4096
#define PREP1_N 41984
#define WT_BYTE (1u << 20)
#define HST_BYTE (8u << 20)

__device__ __forceinline__ u16 f2bf(float x) {
  __bf16 b = (__bf16)x;                 // RNE; pairs into v_cvt_pk_bf16_f32
  return __builtin_bit_cast(u16, b);
}
__device__ __forceinline__ unsigned int pk2(float a, float b) {
  return (unsigned int)f2bf(a) | ((unsigned int)f2bf(b) << 16);
}
__device__ __forceinline__ float sigf(float x) {
  return __fdividef(1.0f, 1.0f + __expf(-x));
}
__device__ __forceinline__ float tanhf_(float x) {
  return 1.0f - __fdividef(2.0f, __expf(2.0f * x) + 1.0f);
}

// Workgroup barrier WITHOUT the vmcnt(0) drain __syncthreads() emits.
// lgkmcnt(0) makes this wave's LDS writes visible; global loads/stores
// stay in flight across the barrier (T4: never drain vmcnt in the loop).
__device__ __forceinline__ void wg_barrier_lds() {
  asm volatile("s_waitcnt lgkmcnt(0)" ::: "memory");
  __builtin_amdgcn_s_barrier();
}

// Pack W_hh / W_ih / W_out / W_lat into MFMA B-fragment order:
// slot(j,t,l) element e = W[n=j*16+(l&15)][k=t*32+8*(l>>4)+e]
__global__ void prep_weights(const float* __restrict__ Whh, const float* __restrict__ Wih,
                             const float* __restrict__ Wout, const float* __restrict__ Wlat,
                             uint4* __restrict__ ws) {
  int i = blockIdx.x * 256 + threadIdx.x;
  if (i >= PREP1_N) return;
  int l = i & 63;
  int c16 = l & 15, g4 = l >> 4;
  const float* src;
  if (i < WIH_O) {                       // W_hh: rowlen 256
    int t = (i >> 6) & 7, j = i >> 9;
    src = Whh + (j * 16 + c16) * 256 + t * 32 + 8 * g4;
  } else if (i < WOUT_O) {               // W_ih: rowlen 32, single k-tile
    int ii = i - WIH_O;
    int j = ii >> 6;
    src = Wih + (j * 16 + c16) * 32 + 8 * g4;
  } else if (i < WLAT_O) {               // W_out: rowlen 256
    int ii = i - WOUT_O;
    int t = (ii >> 6) & 7, j = ii >> 9;
    src = Wout + (j * 16 + c16) * 256 + t * 32 + 8 * g4;
  } else {                               // W_lat: rowlen 64, 2 k-tiles
    int ii = i - WLAT_O;
    int t = (ii >> 6) & 1, j = ii >> 7;
    src = Wlat + (j * 16 + c16) * 64 + t * 32 + 8 * g4;
  }
  uint4 P;
  P.x = pk2(src[0], src[1]);
  P.y = pk2(src[2], src[3]);
  P.z = pk2(src[4], src[5]);
  P.w = pk2(src[6], src[7]);
  ws[i] = P;
}

// Transpose W_sig [32 f][h*256+s] (f32) -> Wt [32 f][s*256+h] (bf16).
__global__ void prep_wt(const float* __restrict__ Wsig, unsigned short* __restrict__ Wt) {
  __shared__ float tile[32][257];
  int f = blockIdx.x >> 3, hb = blockIdx.x & 7;
  int tid = threadIdx.x;  // 256
  const float* src = Wsig + f * (HDIM * SLEN) + hb * 32 * 256;
#pragma unroll
  for (int i = 0; i < 32; ++i) tile[i][tid] = src[i * 256 + tid];
  __syncthreads();
  int s = tid;
  unsigned short tmp[32];
#pragma unroll
  for (int h = 0; h < 32; ++h) tmp[h] = f2bf(tile[h][s]);
  uint4* dst = (uint4*)(Wt + f * 65536 + s * 256 + hb * 32);
  const uint4* tsrc = (const uint4*)tmp;
#pragma unroll
  for (int j = 0; j < 4; ++j) dst[j] = tsrc[j];
}

// Persistent LSTM scan: 64 WGs x 16 batch rows, 16 waves, 256 steps.
// Wave w owns j in {w,16+w,32+w,48+w}; i/f/g/o lane-local. W_hh streamed
// from L2 via a 2-ahead rolling register pipeline; barriers are raw
// s_barrier + lgkmcnt(0) only, so loads/stores overlap the whole step.
__global__ __launch_bounds__(1024, 4) void lstm_scan(
    const float* __restrict__ z, const float* __restrict__ b_lat,
    const float* __restrict__ b_ih, const float* __restrict__ b_hh,
    const float* __restrict__ b_out,
    const uint4* __restrict__ ws, unsigned short* __restrict__ hst,
    float* __restrict__ out) {
  __shared__ __align__(16) uint4 wihl[4096];              // 64KB W_ih frags
  __shared__ __align__(16) uint4 woutb[1024];             // 16KB W_out frags
  __shared__ __align__(16) u16 hbuf[2][16][256];          // 16KB (swizzled)
  __shared__ __align__(16) u16 thbuf[16][256];            // 8KB (swizzled; z-stage)
  __shared__ __align__(16) u16 xbuf[2][16][32];           // 2KB
  __shared__ __align__(16) float mubuf[16][16][32];       // 32KB

  const int tid = threadIdx.x, w = tid >> 6, l = tid & 63;
  const int c16 = l & 15, g4 = l >> 4, r0 = g4 * 4;
  const int wg = blockIdx.x;
  const int swz = (c16 & 7) << 3;

  // one-time LDS fills
  for (int i = tid; i < 4096; i += 1024) wihl[i] = ws[WIH_O + i];
  if (tid < 1024) woutb[tid] = ws[WOUT_O + tid];

  // streamed W_hh bases, biased at kt=4 so imm offsets (kt-4)*1024 fit +-4096
  const uint4* bs[4];
#pragma unroll
  for (int gi = 0; gi < 4; ++gi)
    bs[gi] = ws + WHH_O + ((gi * 16 + w) * 8 + 4) * 64 + l;

  float biasv[4];
#pragma unroll
  for (int gi = 0; gi < 4; ++gi) {
    int n = (gi * 16 + w) * 16 + c16;
    biasv[gi] = b_ih[n] + b_hh[n];
  }
  const int jn = w - 14;
  const float bo = (w >= 14) ? b_out[jn * 16 + c16] : 0.f;

  // ---- init: z -> thbuf staging, x0 = 0 ----
  thbuf[tid >> 6][tid & 63] = f2bf(z[(wg * 16 + (tid >> 6)) * 64 + (tid & 63)]);
  if (tid < 512) xbuf[0][tid >> 5][tid & 31] = 0;
  __syncthreads();

  // hc = z @ W_lat^T + b_lat : wave w computes h-tile j=w, c-tile j=16+w
  float cst[4];
  {
    bf16x8 za0 = *reinterpret_cast<const bf16x8*>(&thbuf[c16][8 * g4]);
    bf16x8 za1 = *reinterpret_cast<const bf16x8*>(&thbuf[c16][32 + 8 * g4]);
    float blh = b_lat[w * 16 + c16];
    float blc = b_lat[256 + w * 16 + c16];
    f32x4 ah = {blh, blh, blh, blh}, ac = {blc, blc, blc, blc};
    ah = MFMA(za0, *reinterpret_cast<const bf16x8*>(ws + WLAT_O + (w * 2 + 0) * 64 + l), ah, 0, 0, 0);
    ah = MFMA(za1, *reinterpret_cast<const bf16x8*>(ws + WLAT_O + (w * 2 + 1) * 64 + l), ah, 0, 0, 0);
    ac = MFMA(za0, *reinterpret_cast<const bf16x8*>(ws + WLAT_O + ((16 + w) * 2 + 0) * 64 + l), ac, 0, 0, 0);
    ac = MFMA(za1, *reinterpret_cast<const bf16x8*>(ws + WLAT_O + ((16 + w) * 2 + 1) * 64 + l), ac, 0, 0, 0);
    const int hc = w * 16 + c16;
#pragma unroll
    for (int v = 0; v < 4; ++v) {
      cst[v] = ac[v];
      int rr = r0 + v;
      hbuf[0][rr][hc ^ ((rr & 7) << 3)] = f2bf(ah[v]);
    }
  }
  __syncthreads();

  // rolling prefetch: preload kt0, kt1
  uint4 pf0[4], pf1[4];
#pragma unroll
  for (int gi = 0; gi < 4; ++gi) pf0[gi] = bs[gi][(0 - 4) * 64];
#pragma unroll
  for (int gi = 0; gi < 4; ++gi) pf1[gi] = bs[gi][(1 - 4) * 64];

  // ---- the scan ----
  for (int s = 0; s < SLEN; ++s) {
    const int pb = s & 1;
    // phase 1: gates — rolling 2-ahead W_hh stream, all indices static
    f32x4 acc[4];
#pragma unroll
    for (int gi = 0; gi < 4; ++gi)
      acc[gi] = (f32x4){biasv[gi], biasv[gi], biasv[gi], biasv[gi]};
#pragma unroll
    for (int kt = 0; kt < 8; ++kt) {
      uint4 pf2[4];
      const int ktn = (kt + 2) & 7;   // kt6/kt7 issue kt0/kt1 for the NEXT step
#pragma unroll
      for (int gi = 0; gi < 4; ++gi) pf2[gi] = bs[gi][(ktn - 4) * 64];
      bf16x8 afr = *reinterpret_cast<const bf16x8*>(&hbuf[pb][c16][(kt * 32 + 8 * g4) ^ swz]);
#pragma unroll
      for (int gi = 0; gi < 4; ++gi)
        acc[gi] = MFMA(afr, __builtin_bit_cast(bf16x8, pf0[gi]), acc[gi], 0, 0, 0);
#pragma unroll
      for (int gi = 0; gi < 4; ++gi) { pf0[gi] = pf1[gi]; pf1[gi] = pf2[gi]; }
    }
    {
      bf16x8 xfr = *reinterpret_cast<const bf16x8*>(&xbuf[pb][c16][8 * g4]);
#pragma unroll
      for (int gi = 0; gi < 4; ++gi)
        acc[gi] = MFMA(xfr, *reinterpret_cast<const bf16x8*>(&wihl[(gi * 16 + w) * 64 + l]), acc[gi], 0, 0, 0);
    }
    // elementwise: lane owns 4 batch rows x 1 h-col
    {
      const int hc = w * 16 + c16;
#pragma unroll
      for (int v = 0; v < 4; ++v) {
        float iv = acc[0][v];
        float fv = acc[1][v];
        float gv = acc[2][v];
        float ov = acc[3][v];
        float cc = sigf(fv) * cst[v] + sigf(iv) * tanhf_(gv);
        cst[v] = cc;
        float hh = sigf(ov) * tanhf_(cc);
        float th = tanhf_(hh);
        int rr = r0 + v;
        int sc = hc ^ ((rr & 7) << 3);
        hbuf[pb ^ 1][rr][sc] = f2bf(hh);
        thbuf[rr][sc] = f2bf(th);
      }
    }
    wg_barrier_lds();  // B1 (no vmcnt drain)
    // phase 3: waves 14-15: x_{s+1} = tanh(h_{s+1}) @ W_out^T -> xbuf + mubuf;
    //          waves 0-7:   h_{s+1} -> hst (coalesced bf16, fire-and-forget)
    if (w >= 14) {
      f32x4 xacc = {bo, bo, bo, bo};
#pragma unroll
      for (int t = 0; t < 8; ++t) {
        bf16x8 ta = *reinterpret_cast<const bf16x8*>(&thbuf[c16][(t * 32 + 8 * g4) ^ swz]);
        xacc = MFMA(ta, *reinterpret_cast<const bf16x8*>(&woutb[(jn * 8 + t) * 64 + l]), xacc, 0, 0, 0);
      }
      const int f = jn * 16 + c16;
      const int sw = s & 15;
#pragma unroll
      for (int v = 0; v < 4; ++v) {
        int rr = r0 + v;
        xbuf[pb ^ 1][rr][f] = f2bf(xacc[v]);
        mubuf[sw][rr][f] = xacc[v];
      }
    } else if (w < 8) {
      int r = tid >> 5;
      int h0 = (tid & 31) * 8;
      uint4 d = *reinterpret_cast<const uint4*>(&hbuf[pb ^ 1][r][h0 ^ ((r & 7) << 3)]);
      *reinterpret_cast<uint4*>(hst + ((wg * 16 + r) << 16) + (s << 8) + h0) = d;
    }
    wg_barrier_lds();  // B2 (no vmcnt drain)
    if ((s & 15) == 15 && tid < 512) {
      // flush 16 steps of mu: thread (b,f) writes 16 consecutive s -> 64B line
      int b = tid >> 5, f = tid & 31;
      float* dst = out + ((wg * 16 + b) << 13) + (f << 8) + (s - 15);
#pragma unroll
      for (int j4 = 0; j4 < 4; ++j4) {
        f32x4 vv;
#pragma unroll
        for (int jj = 0; jj < 4; ++jj) vv[jj] = mubuf[j4 * 4 + jj][b][f];
        *reinterpret_cast<f32x4*>(dst + j4 * 4) = vv;
      }
      // safe: next write to these mubuf slots is after B1 of step s+1, and
      // this wave's flush ds_reads are lgkm-drained at that barrier.
    }
  }
}

// sigma = softplus(hs_flat @ W_sig^T + b_sig)
// 256 WGs x 4 batch rows; each wave owns a 8192-wide k-chunk; LDS reduce.
__global__ __launch_bounds__(512) void sigma_gemm(
    const unsigned short* __restrict__ hst, const unsigned short* __restrict__ Wt,
    const float* __restrict__ b_sig, float* __restrict__ out) {
  __shared__ float sred[8][16][32];  // 16KB
  const int tid = threadIdx.x;
  const int w = tid >> 6;
  const int l = tid & 63;
  const int c16 = l & 15;
  const int g4 = l >> 4;
  const int wg = blockIdx.x;

  const unsigned short* ap =
      hst + (((wg << 2) + (c16 & 3)) << 16) + ((w * 32) << 8) + (g4 << 3);
  const unsigned short* bp0 = Wt + (c16 << 16) + ((w * 32) << 8) + (g4 << 3);
  const unsigned short* bp1 = Wt + ((16 + c16) << 16) + ((w * 32) << 8) + (g4 << 3);

  f32x4 a0 = {0.f, 0.f, 0.f, 0.f}, a1 = {0.f, 0.f, 0.f, 0.f};
#pragma unroll 8
  for (int kk = 0; kk < 256; ++kk) {
    int off = ((kk >> 3) << 8) + ((kk & 7) << 5);
    bf16x8 av = *reinterpret_cast<const bf16x8*>(ap + off);
    a0 = MFMA(av, *reinterpret_cast<const bf16x8*>(bp0 + off), a0, 0, 0, 0);
    a1 = MFMA(av, *reinterpret_cast<const bf16x8*>(bp1 + off), a1, 0, 0, 0);
  }
#pragma unroll
  for (int v = 0; v < 4; ++v) {
    sred[w][g4 * 4 + v][c16] = a0[v];
    sred[w][g4 * 4 + v][16 + c16] = a1[v];
  }
  __syncthreads();
  int b = tid >> 5, f = tid & 31;
  if (b < 4) {
    float acc = b_sig[f];
#pragma unroll
    for (int ww = 0; ww < 8; ++ww) acc += sred[ww][b][f];
    float sp = fmaxf(acc, 0.0f) + log1pf(__expf(-fabsf(acc)));
    out[BATCH * NF * SLEN + ((wg << 2) + b) * NF + f] = sp;
  }
}

extern "C" void kernel_launch(void* const* d_in, const int* in_sizes, int n_in,
                              void* d_out, int out_size, void* d_ws, size_t ws_size,
                              hipStream_t stream) {
  (void)in_sizes; (void)n_in; (void)out_size; (void)ws_size;
  const float* z     = (const float*)d_in[0];
  const float* W_lat = (const float*)d_in[1];
  const float* b_lat = (const float*)d_in[2];
  const float* W_ih  = (const float*)d_in[3];
  const float* b_ih  = (const float*)d_in[4];
  const float* W_hh  = (const float*)d_in[5];
  const float* b_hh  = (const float*)d_in[6];
  const float* W_out = (const float*)d_in[7];
  const float* b_out = (const float*)d_in[8];
  const float* W_sig = (const float*)d_in[9];
  const float* b_sig = (const float*)d_in[10];
  char* wsb = (char*)d_ws;
  uint4* ws = (uint4*)wsb;
  unsigned short* Wt  = (unsigned short*)(wsb + WT_BYTE);
  unsigned short* hst = (unsigned short*)(wsb + HST_BYTE);
  float* out = (float*)d_out;

  prep_weights<<<(PREP1_N + 255) / 256, 256, 0, stream>>>(W_hh, W_ih, W_out, W_lat, ws);
  prep_wt<<<256, 256, 0, stream>>>(W_sig, Wt);
  lstm_scan<<<64, 1024, 0, stream>>>(z, b_lat, b_ih, b_hh, b_out, ws, hst, out);
  sigma_gemm<<<256, 512, 0, stream>>>(hst, Wt, b_sig, out);
}